// Round 1
// 483.063 us; speedup vs baseline: 1.0006x; 1.0006x over previous
//
#include <hip/hip_runtime.h>

#define B 32
#define C 512
#define HW 4096            // 64*64
#define K 256              // int(0.5 * C)
// spatial mean (1/HW) folded with mask mean (1/(B*K)): 1/(4096*8192) = 2^-25, exact
#define INV_SCALE (1.f / 33554432.f)

typedef float f4_t __attribute__((ext_vector_type(4)));

__inline__ __device__ float wave_reduce(float v) {
    #pragma unroll
    for (int o = 32; o > 0; o >>= 1) v += __shfl_down(v, o, 64);
    return v;
}

// Kernel 1: ONE WAVE per (b,c) plane, 4 planes per 256-thread block.
// A plane is 4096 floats = 16 float4 per lane; the whole reduction is
// wave-local: no LDS, no __syncthreads, no cross-wave tail. Nontemporal
// loads: data is single-use and 2x the L3 size. Block 0 also zeroes the
// scalar output (stream-ordered before kernel 2's atomicAdd), replacing
// the hipMemsetAsync dispatch.
__global__ __launch_bounds__(256) void plane_reduce(
        const float* __restrict__ in, const float* __restrict__ tgt,
        float* __restrict__ norm2, float* __restrict__ ssd,
        float* __restrict__ out) {
    if (blockIdx.x == 0 && threadIdx.x == 0) out[0] = 0.f;

    const int wid  = threadIdx.x >> 6;
    const int lane = threadIdx.x & 63;
    const int plane = blockIdx.x * 4 + wid;       // grid = B*C/4 = 4096
    const size_t base = (size_t)plane * HW;
    const f4_t* __restrict__ in4 = (const f4_t*)(in  + base);
    const f4_t* __restrict__ tg4 = (const f4_t*)(tgt + base);

    float t2 = 0.f, d2 = 0.f;
    #pragma unroll 4
    for (int i = 0; i < 16; ++i) {                // 1024 float4 / 64 lanes
        const int j = lane + i * 64;
        const f4_t a = __builtin_nontemporal_load(in4 + j);
        const f4_t t = __builtin_nontemporal_load(tg4 + j);
        const float dx = a.x - t.x, dy = a.y - t.y, dz = a.z - t.z, dw = a.w - t.w;
        t2 += t.x * t.x + t.y * t.y + t.z * t.z + t.w * t.w;
        d2 += dx * dx + dy * dy + dz * dz + dw * dw;
    }

    t2 = wave_reduce(t2);
    d2 = wave_reduce(d2);
    if (lane == 0) {
        norm2[plane] = t2;
        ssd[plane]   = d2;
    }
}

// Kernel 2 (fused topk + masked sum + finalize): one block per batch.
// Exact top-k by rank with jax tie-breaking (equal norm -> lower index).
// Masked block-sum of ssd, then one scaled atomicAdd into out[0]
// (zeroed by plane_reduce block 0 earlier in the stream).
__global__ __launch_bounds__(C) void topk_mask_sum(
        const float* __restrict__ norm2, const float* __restrict__ ssd,
        float* __restrict__ out) {
    __shared__ float sn[C];
    __shared__ float red[C / 64];
    const int b = blockIdx.x, c = threadIdx.x;
    sn[c] = norm2[b * C + c];
    __syncthreads();

    const float my = sn[c];
    int rank = 0;
    #pragma unroll 8
    for (int j = 0; j < C; ++j) {
        const float o = sn[j];
        rank += (o > my) || (o == my && j < c);
    }
    float v = (rank < K) ? ssd[b * C + c] : 0.f;

    v = wave_reduce(v);
    const int lane = c & 63, wid = c >> 6;
    if (lane == 0) red[wid] = v;
    __syncthreads();
    if (c == 0) {
        float s = 0.f;
        #pragma unroll
        for (int w = 0; w < C / 64; ++w) s += red[w];
        atomicAdd(out, s * INV_SCALE);
    }
}

extern "C" void kernel_launch(void* const* d_in, const int* in_sizes, int n_in,
                              void* d_out, int out_size, void* d_ws, size_t ws_size,
                              hipStream_t stream) {
    const float* in  = (const float*)d_in[0];
    const float* tgt = (const float*)d_in[1];
    float* out = (float*)d_out;

    float* norm2 = (float*)d_ws;            // B*C floats
    float* ssd   = norm2 + B * C;           // B*C floats

    plane_reduce<<<B * C / 4, 256, 0, stream>>>(in, tgt, norm2, ssd, out);
    topk_mask_sum<<<B, C, 0, stream>>>(norm2, ssd, out);
}